// Round 4
// baseline (413.288 us; speedup 1.0000x reference)
//
#include <hip/hip_runtime.h>
#include <cstddef>
#include <cstdint>

// Problem constants (fixed by reference file)
#define B_      256
#define V_      128000
#define T_      16
#define TOPK_   100
#define NF4     (V_ / 4)        // 32000 float4 per row
#define NHIST   4096
#define SLICES  5
#define F4S     (NF4 / SLICES)  // 6400 float4 per slice (25 iters x 256 thr)
#define ITERS   (F4S / 256)     // 25
#define UNROLL  5
#define CAP_BLK 256             // per-block candidate cap (mean ~51, 28 sigma)
#define CAP_ROW 2048            // >= SLICES*CAP_BLK = 1280
#define T0      0.998f          // expected ~256 candidates/row

// ws layout: [0,1024)      int ws_cnt[B_]
//            [1024,2048)   int ws_of[B_]     (overflow flags)
//            [2048,3072)   int ws_done[B_]   (slice arrival counters)
//            [4096,...)    float ws_cand[B_][CAP_ROW]   (2 MB)

__global__ void zero_kernel(float* o, int* ws_cnt, int* ws_of, int* ws_done) {
    int t = threadIdx.x;
    if (t < 3) o[t] = 0.f;
    if (t < B_) { ws_cnt[t] = 0; ws_of[t] = 0; ws_done[t] = 0; }
}

// Single fused kernel: 1280 blocks x 256 threads.
// Phase 1 (all blocks): stream one slice, stage hits in LDS, publish to ws.
// Phase 2 (last-arriving block per row): top-100 rank-select + target/margin.
__global__ __launch_bounds__(256) void fused_kernel(
        const float* __restrict__ sparse,
        const int*   __restrict__ tids,
        float*       __restrict__ ws_cand,
        int*         __restrict__ ws_cnt,
        int*         __restrict__ ws_of,
        int*         __restrict__ ws_done,
        float*       __restrict__ out) {
    __shared__ int   s_ids[T_];
    __shared__ float s_buf[CAP_BLK];
    __shared__ int   s_n;
    __shared__ int   s_gbase;
    __shared__ int   s_last;
    // 16 KB overlay: candidate array (floats) / fallback histogram (uints).
    __shared__ float s_cand[NHIST];
    __shared__ int   s_cnt;
    __shared__ int   s_bstar;
    __shared__ float s_red[4];

    const int blk = blockIdx.x;
    const int row = blk / SLICES;
    const int sl  = blk - row * SLICES;
    const int tid = threadIdx.x;

    if (tid < T_) s_ids[tid] = tids[row * T_ + tid];
    if (tid == 0) s_n = 0;
    __syncthreads();

    const float* __restrict__ rp = sparse + (size_t)row * V_;
    const float4* __restrict__ rp4 = (const float4*)rp;
    const int base = sl * F4S + tid;

    // ---- phase 1: streaming collect (5 independent float4 loads in flight)
    for (int it = 0; it < ITERS; it += UNROLL) {
        float4 v[UNROLL];
        #pragma unroll
        for (int u = 0; u < UNROLL; ++u)
            v[u] = rp4[base + (it + u) * 256];
        #pragma unroll
        for (int u = 0; u < UNROLL; ++u) {
            const int col = (base + (it + u) * 256) << 2;
            float xs[4] = {v[u].x, v[u].y, v[u].z, v[u].w};
            #pragma unroll
            for (int c = 0; c < 4; ++c) {
                float x = xs[c];
                if (x >= T0) {
                    int cc = col + c;
                    bool is_t = false;
                    #pragma unroll
                    for (int j = 0; j < T_; ++j) is_t |= (cc == s_ids[j]);
                    if (!is_t) {
                        int k = atomicAdd(&s_n, 1);   // LDS atomic
                        if (k < CAP_BLK) s_buf[k] = x;
                    }
                }
            }
        }
    }
    __syncthreads();

    int n = min(s_n, CAP_BLK);
    if (tid == 0) {
        s_gbase = atomicAdd(ws_cnt + row, n);          // one global atomic/block
        if (s_n > CAP_BLK) atomicExch(ws_of + row, 1); // exactness guard
    }
    __syncthreads();
    {
        int gbase = s_gbase;                            // gbase+n <= 1280 < CAP_ROW
        float* __restrict__ cand = ws_cand + (size_t)row * CAP_ROW;
        for (int i = tid; i < n; i += 256) cand[gbase + i] = s_buf[i];
    }

    // ---- arrive; last block per row proceeds to phase 2
    __threadfence();                                    // release our writes
    if (tid == 0) {
        int prev = atomicAdd(ws_done + row, 1);
        s_last = (prev == SLICES - 1) ? 1 : 0;
    }
    __syncthreads();
    if (!s_last) return;
    __threadfence();                                    // acquire others' writes

    // ---- phase 2: per-row reduction (exactly one block per row) ----

    // target + margin losses (threads 0..15; row is L2/L3-hot)
    if (tid < T_) {
        float x  = rp[s_ids[tid]];
        float tl = -logf(x + 1e-8f);
        float ml = fmaxf(1.0f - x, 0.0f);
        #pragma unroll
        for (int off = 8; off > 0; off >>= 1) {
            tl += __shfl_down(tl, off);
            ml += __shfl_down(ml, off);
        }
        if (tid == 0) {
            atomicAdd(out + 0, tl * (1.0f / (B_ * T_)));
            atomicAdd(out + 1, ml * (1.0f / (B_ * T_)));
        }
    }

    int cnt = atomicAdd(ws_cnt + row, 0);               // coherent read
    int of  = atomicAdd(ws_of + row, 0);
    bool bad = (cnt < TOPK_) || (cnt > CAP_ROW) || (of != 0);

    if (!bad) {
        const float* cand = ws_cand + (size_t)row * CAP_ROW;
        for (int i = tid; i < cnt; i += 256) s_cand[i] = cand[i];
        __syncthreads();
    } else {
        // exact histogram fallback (astronomically rare for uniform data).
        // s_hist aliases s_cand storage; hist is dead before s_cand writes.
        unsigned* s_hist = (unsigned*)s_cand;
        for (int i = tid; i < NHIST; i += 256) s_hist[i] = 0u;
        if (tid == 0) s_cnt = 0;
        __syncthreads();
        for (int i = tid; i < NF4; i += 256) {
            float4 v = rp4[i];
            float xs[4] = {v.x, v.y, v.z, v.w};
            #pragma unroll
            for (int c = 0; c < 4; ++c) {
                int b = (int)(xs[c] * (float)NHIST);
                b = min(max(b, 0), NHIST - 1);
                atomicAdd(&s_hist[b], 1u);
            }
        }
        __syncthreads();
        if (tid == 0) {
            for (int j = 0; j < T_; ++j) {
                int id = s_ids[j];
                bool dup = false;
                for (int q = 0; q < j; ++q) dup = dup || (s_ids[q] == id);
                if (!dup) {
                    int b = (int)(rp[id] * (float)NHIST);
                    b = min(max(b, 0), NHIST - 1);
                    s_hist[b]--;
                }
            }
            int acc = 0, b = NHIST - 1;
            for (; b >= 0; --b) {
                acc += (int)s_hist[b];
                if (acc >= TOPK_) break;
            }
            s_bstar = max(b, 0);
        }
        __syncthreads();
        int bstar = s_bstar;
        for (int i = tid; i < NF4; i += 256) {
            float4 v = rp4[i];
            int col = i << 2;
            float xs[4] = {v.x, v.y, v.z, v.w};
            #pragma unroll
            for (int c = 0; c < 4; ++c) {
                float x = xs[c];
                int b = (int)(x * (float)NHIST);
                b = min(max(b, 0), NHIST - 1);
                if (b >= bstar) {
                    int cc = col + c;
                    bool is_t = false;
                    #pragma unroll
                    for (int j = 0; j < T_; ++j) is_t |= (cc == s_ids[j]);
                    if (!is_t) {
                        int k = atomicAdd(&s_cnt, 1);
                        if (k < CAP_ROW) s_cand[k] = x;
                    }
                }
            }
        }
        __syncthreads();
        cnt = min(s_cnt, CAP_ROW);
    }

    // O(n^2) exact rank-select (n ~ 256): include x_i iff rank < TOPK_.
    // Inner index j is wave-uniform -> LDS broadcast, conflict-free.
    float sum = 0.f;
    for (int i = tid; i < cnt; i += 256) {
        float x = s_cand[i];
        int rank = 0;
        for (int j = 0; j < cnt; ++j) {
            float y = s_cand[j];
            rank += (y > x) ? 1 : ((y == x && j < i) ? 1 : 0);
        }
        if (rank < TOPK_) sum += x;
    }

    #pragma unroll
    for (int off = 32; off > 0; off >>= 1) sum += __shfl_down(sum, off);
    if ((tid & 63) == 0) s_red[tid >> 6] = sum;
    __syncthreads();
    if (tid == 0) {
        float tot = s_red[0] + s_red[1] + s_red[2] + s_red[3];
        atomicAdd(out + 2, tot * (1.0f / (B_ * TOPK_)));
    }
}

extern "C" void kernel_launch(void* const* d_in, const int* in_sizes, int n_in,
                              void* d_out, int out_size, void* d_ws, size_t ws_size,
                              hipStream_t stream) {
    const float* sparse = (const float*)d_in[0];
    const int*   tids   = (const int*)d_in[1];
    float*       out    = (float*)d_out;
    int*         ws_cnt  = (int*)d_ws;
    int*         ws_of   = (int*)((char*)d_ws + 1024);
    int*         ws_done = (int*)((char*)d_ws + 2048);
    float*       ws_cand = (float*)((char*)d_ws + 4096);

    zero_kernel<<<1, 256, 0, stream>>>(out, ws_cnt, ws_of, ws_done);
    fused_kernel<<<B_ * SLICES, 256, 0, stream>>>(sparse, tids, ws_cand,
                                                  ws_cnt, ws_of, ws_done, out);
}

// Round 5
// 213.210 us; speedup vs baseline: 1.9384x; 1.9384x over previous
//
#include <hip/hip_runtime.h>
#include <cstddef>
#include <cstdint>

// Problem constants (fixed by reference file)
#define B_      256
#define V_      128000
#define T_      16
#define TOPK_   100
#define NF4     (V_ / 4)        // 32000 float4 per row
#define NHIST   4096
#define SLICES  25
#define F4S     (NF4 / SLICES)  // 1280 float4 per slice
#define ITERS   (F4S / 256)     // 5 (fully unrolled)
#define CAP_BLK 128             // per-block cap (mean ~10 hits, huge margin)
#define CAP_ROW 4096            // >= worst-case SLICES*CAP_BLK kept slots
#define T0      0.998f          // expected ~256 candidates/row

// ws layout: [0,1024)      int ws_cnt[B_]
//            [1024,2048)   int ws_of[B_]   (overflow flags)
//            [4096,...)    float ws_cand[B_][CAP_ROW]   (4 MB)
// NOTE (R4 lesson): cross-block handoff INSIDE a kernel needs agent-scope
// fences = per-XCD L2 writeback/invalidate per block on gfx950 — ~200us of
// stall. Kernel boundaries provide the flush once. Keep 3 launches.

__global__ void zero_kernel(float* o, int* ws_cnt, int* ws_of) {
    int t = threadIdx.x;
    if (t < 3) o[t] = 0.f;
    if (t < B_) { ws_cnt[t] = 0; ws_of[t] = 0; }
}

// Kernel A: streaming collect. 6400 blocks x 256 threads, 5 float4/thread.
// All 5 loads issue before any scan; hits staged via LDS atomic; one global
// atomic per block.
__global__ __launch_bounds__(256) void collect_kernel(
        const float* __restrict__ sparse,
        const int*   __restrict__ tids,
        float*       __restrict__ ws_cand,
        int*         __restrict__ ws_cnt,
        int*         __restrict__ ws_of) {
    __shared__ int   s_ids[T_];
    __shared__ float s_buf[CAP_BLK];
    __shared__ int   s_n;
    __shared__ int   s_gbase;

    const int blk = blockIdx.x;
    const int row = blk / SLICES;
    const int sl  = blk - row * SLICES;
    const int tid = threadIdx.x;

    if (tid < T_) s_ids[tid] = tids[row * T_ + tid];
    if (tid == 0) s_n = 0;
    __syncthreads();

    const float4* __restrict__ rp4 = (const float4*)(sparse + (size_t)row * V_);
    const int base = sl * F4S + tid;

    float4 v[ITERS];
    #pragma unroll
    for (int u = 0; u < ITERS; ++u)
        v[u] = rp4[base + u * 256];

    #pragma unroll
    for (int u = 0; u < ITERS; ++u) {
        const int col = (base + u * 256) << 2;
        float xs[4] = {v[u].x, v[u].y, v[u].z, v[u].w};
        #pragma unroll
        for (int c = 0; c < 4; ++c) {
            float x = xs[c];
            if (x >= T0) {
                int cc = col + c;
                bool is_t = false;
                #pragma unroll
                for (int j = 0; j < T_; ++j) is_t |= (cc == s_ids[j]);
                if (!is_t) {
                    int k = atomicAdd(&s_n, 1);    // LDS atomic
                    if (k < CAP_BLK) s_buf[k] = x;
                }
            }
        }
    }
    __syncthreads();

    int n = min(s_n, CAP_BLK);
    if (tid == 0) {
        s_gbase = atomicAdd(ws_cnt + row, n);          // one global atomic/block
        if (s_n > CAP_BLK) atomicExch(ws_of + row, 1); // exactness guard
    }
    __syncthreads();
    int gbase = s_gbase;                               // <= SLICES*CAP_BLK-? bounded below
    float* __restrict__ cand = ws_cand + (size_t)row * CAP_ROW;
    for (int i = tid; i < n; i += 256) {
        int idx = gbase + i;
        if (idx < CAP_ROW) cand[idx] = s_buf[i];
        else if (tid == 0) atomicExch(ws_of + row, 1); // belt & suspenders
    }
}

// Kernel B: per-row top-100 via O(n^2) rank-select + target/margin losses.
__global__ __launch_bounds__(256) void reduce_kernel(
        const float* __restrict__ sparse,
        const int*   __restrict__ tids,
        const float* __restrict__ ws_cand,
        const int*   __restrict__ ws_cnt,
        const int*   __restrict__ ws_of,
        float*       __restrict__ out) {
    __shared__ float s_cand[CAP_ROW];   // 16 KB; fallback hist aliases this
    __shared__ int   s_ids[T_];
    __shared__ int   s_cnt;
    __shared__ int   s_bstar;
    __shared__ float s_red[4];

    const int row = blockIdx.x;
    const int tid = threadIdx.x;
    const float* __restrict__ rp = sparse + (size_t)row * V_;

    if (tid < T_) s_ids[tid] = tids[row * T_ + tid];
    __syncthreads();

    // ---- target + margin losses (threads 0..15; row is L2/L3-hot) ----
    if (tid < T_) {
        float x  = rp[s_ids[tid]];
        float tl = -logf(x + 1e-8f);
        float ml = fmaxf(1.0f - x, 0.0f);
        #pragma unroll
        for (int off = 8; off > 0; off >>= 1) {
            tl += __shfl_down(tl, off);
            ml += __shfl_down(ml, off);
        }
        if (tid == 0) {
            atomicAdd(out + 0, tl * (1.0f / (B_ * T_)));
            atomicAdd(out + 1, ml * (1.0f / (B_ * T_)));
        }
    }

    int cnt = ws_cnt[row];
    bool bad = (cnt < TOPK_) || (cnt > CAP_ROW) || (ws_of[row] != 0);

    if (!bad) {
        const float* cand = ws_cand + (size_t)row * CAP_ROW;
        for (int i = tid; i < cnt; i += 256) s_cand[i] = cand[i];
        __syncthreads();
    } else {
        // exact histogram fallback (astronomically rare for uniform data)
        unsigned* s_hist = (unsigned*)s_cand;
        for (int i = tid; i < NHIST; i += 256) s_hist[i] = 0u;
        if (tid == 0) s_cnt = 0;
        __syncthreads();
        const float4* rp4 = (const float4*)rp;
        for (int i = tid; i < NF4; i += 256) {
            float4 v = rp4[i];
            float xs[4] = {v.x, v.y, v.z, v.w};
            #pragma unroll
            for (int c = 0; c < 4; ++c) {
                int b = (int)(xs[c] * (float)NHIST);
                b = min(max(b, 0), NHIST - 1);
                atomicAdd(&s_hist[b], 1u);
            }
        }
        __syncthreads();
        if (tid == 0) {
            for (int j = 0; j < T_; ++j) {
                int id = s_ids[j];
                bool dup = false;
                for (int q = 0; q < j; ++q) dup = dup || (s_ids[q] == id);
                if (!dup) {
                    int b = (int)(rp[id] * (float)NHIST);
                    b = min(max(b, 0), NHIST - 1);
                    s_hist[b]--;
                }
            }
            int acc = 0, b = NHIST - 1;
            for (; b >= 0; --b) {
                acc += (int)s_hist[b];
                if (acc >= TOPK_) break;
            }
            s_bstar = max(b, 0);
        }
        __syncthreads();
        int bstar = s_bstar;
        for (int i = tid; i < NF4; i += 256) {
            float4 v = rp4[i];
            int col = i << 2;
            float xs[4] = {v.x, v.y, v.z, v.w};
            #pragma unroll
            for (int c = 0; c < 4; ++c) {
                float x = xs[c];
                int b = (int)(x * (float)NHIST);
                b = min(max(b, 0), NHIST - 1);
                if (b >= bstar) {
                    int cc = col + c;
                    bool is_t = false;
                    #pragma unroll
                    for (int j = 0; j < T_; ++j) is_t |= (cc == s_ids[j]);
                    if (!is_t) {
                        int k = atomicAdd(&s_cnt, 1);
                        if (k < CAP_ROW) s_cand[k] = x;
                    }
                }
            }
        }
        __syncthreads();
        cnt = min(s_cnt, CAP_ROW);
    }

    // ---- O(n^2) exact rank-select (n ~ 256): include x_i iff rank < TOPK_.
    // Inner index j is wave-uniform -> LDS broadcast, conflict-free.
    float sum = 0.f;
    for (int i = tid; i < cnt; i += 256) {
        float x = s_cand[i];
        int rank = 0;
        for (int j = 0; j < cnt; ++j) {
            float y = s_cand[j];
            rank += (y > x) ? 1 : ((y == x && j < i) ? 1 : 0);
        }
        if (rank < TOPK_) sum += x;
    }

    #pragma unroll
    for (int off = 32; off > 0; off >>= 1) sum += __shfl_down(sum, off);
    if ((tid & 63) == 0) s_red[tid >> 6] = sum;
    __syncthreads();
    if (tid == 0) {
        float tot = s_red[0] + s_red[1] + s_red[2] + s_red[3];
        atomicAdd(out + 2, tot * (1.0f / (B_ * TOPK_)));
    }
}

extern "C" void kernel_launch(void* const* d_in, const int* in_sizes, int n_in,
                              void* d_out, int out_size, void* d_ws, size_t ws_size,
                              hipStream_t stream) {
    const float* sparse = (const float*)d_in[0];
    const int*   tids   = (const int*)d_in[1];
    float*       out    = (float*)d_out;
    int*         ws_cnt  = (int*)d_ws;
    int*         ws_of   = (int*)((char*)d_ws + 1024);
    float*       ws_cand = (float*)((char*)d_ws + 4096);

    zero_kernel<<<1, 256, 0, stream>>>(out, ws_cnt, ws_of);
    collect_kernel<<<B_ * SLICES, 256, 0, stream>>>(sparse, tids, ws_cand, ws_cnt, ws_of);
    reduce_kernel<<<B_, 256, 0, stream>>>(sparse, tids, ws_cand, ws_cnt, ws_of, out);
}

// Round 6
// 212.822 us; speedup vs baseline: 1.9419x; 1.0018x over previous
//
#include <hip/hip_runtime.h>
#include <cstddef>
#include <cstdint>

// Problem constants (fixed by reference file)
#define B_      256
#define V_      128000
#define T_      16
#define TOPK_   100
#define NF4     (V_ / 4)        // 32000 float4 per row
#define NHIST   4096
#define SLICES  25
#define F4S     (NF4 / SLICES)  // 1280 float4 per slice
#define ITERS   (F4S / 256)     // 5 (fully unrolled)
#define CAP_BLK 32              // per-block cap (Poisson mean ~2.6 hits)
#define NBLK    (B_ * SLICES)   // 6400
#define T0      0.998f          // expected ~256 candidates/row

// ws layout: [0, 25600)     int   ws_bcnt[NBLK]          (raw per-block count)
//            [32768, ...)   float ws_cand[NBLK][CAP_BLK] (819 KB)
// No state needs pre-zeroing: every collect block writes its own slots.
// R4 lesson (kept): no cross-block handoff inside a kernel on gfx950 —
// agent-scope fences drain per-XCD L2; the kernel boundary is the cheap fence.

// Kernel A: streaming collect. 6400 blocks x 256 threads, 5 float4/thread.
// Atomic-free publish to fixed per-block slots. Block 0 zeroes the outputs
// (safe: kernel boundary orders collect before reduce's atomics).
__global__ __launch_bounds__(256) void collect_kernel(
        const float* __restrict__ sparse,
        const int*   __restrict__ tids,
        float*       __restrict__ ws_cand,
        int*         __restrict__ ws_bcnt,
        float*       __restrict__ out) {
    __shared__ int   s_ids[T_];
    __shared__ float s_buf[CAP_BLK];
    __shared__ int   s_n;

    const int blk = blockIdx.x;
    const int row = blk / SLICES;
    const int sl  = blk - row * SLICES;
    const int tid = threadIdx.x;

    if (blk == 0 && tid < 3) out[tid] = 0.f;

    if (tid < T_) s_ids[tid] = tids[row * T_ + tid];
    if (tid == 0) s_n = 0;
    __syncthreads();

    const float4* __restrict__ rp4 = (const float4*)(sparse + (size_t)row * V_);
    const int base = sl * F4S + tid;

    float4 v[ITERS];
    #pragma unroll
    for (int u = 0; u < ITERS; ++u)
        v[u] = rp4[base + u * 256];

    #pragma unroll
    for (int u = 0; u < ITERS; ++u) {
        // max4 prefilter: common case (99.2%) is one max-tree + one branch
        float m = fmaxf(fmaxf(v[u].x, v[u].y), fmaxf(v[u].z, v[u].w));
        if (m >= T0) {
            const int col = (base + u * 256) << 2;
            float xs[4] = {v[u].x, v[u].y, v[u].z, v[u].w};
            #pragma unroll
            for (int c = 0; c < 4; ++c) {
                float x = xs[c];
                if (x >= T0) {
                    int cc = col + c;
                    bool is_t = false;
                    #pragma unroll
                    for (int j = 0; j < T_; ++j) is_t |= (cc == s_ids[j]);
                    if (!is_t) {
                        int k = atomicAdd(&s_n, 1);    // LDS atomic, rare
                        if (k < CAP_BLK) s_buf[k] = x;
                    }
                }
            }
        }
    }
    __syncthreads();

    int n = s_n;
    if (tid == 0) ws_bcnt[blk] = n;                    // raw count (may exceed cap)
    if (tid < n && tid < CAP_BLK)
        ws_cand[(size_t)blk * CAP_BLK + tid] = s_buf[tid];
}

// Kernel B: per-row top-100 via O(n^2) rank-select + target/margin losses.
__global__ __launch_bounds__(256) void reduce_kernel(
        const float* __restrict__ sparse,
        const int*   __restrict__ tids,
        const float* __restrict__ ws_cand,
        const int*   __restrict__ ws_bcnt,
        float*       __restrict__ out) {
    __shared__ float s_cand[NHIST];     // 16 KB; fallback hist aliases this
    __shared__ int   s_ids[T_];
    __shared__ int   s_cnts[SLICES];
    __shared__ int   s_off[SLICES + 1];
    __shared__ int   s_bad;
    __shared__ int   s_cnt;
    __shared__ int   s_bstar;
    __shared__ float s_red[4];

    const int row = blockIdx.x;
    const int tid = threadIdx.x;
    const float* __restrict__ rp = sparse + (size_t)row * V_;

    if (tid < T_) s_ids[tid] = tids[row * T_ + tid];
    if (tid < SLICES) s_cnts[tid] = ws_bcnt[row * SLICES + tid];
    __syncthreads();

    // ---- target + margin losses (threads 0..15; row is L2/L3-hot) ----
    if (tid < T_) {
        float x  = rp[s_ids[tid]];
        float tl = -logf(x + 1e-8f);
        float ml = fmaxf(1.0f - x, 0.0f);
        #pragma unroll
        for (int off = 8; off > 0; off >>= 1) {
            tl += __shfl_down(tl, off);
            ml += __shfl_down(ml, off);
        }
        if (tid == 0) {
            atomicAdd(out + 0, tl * (1.0f / (B_ * T_)));
            atomicAdd(out + 1, ml * (1.0f / (B_ * T_)));
        }
    }

    // ---- prefix over the 25 per-slice counts ----
    if (tid == 0) {
        int acc = 0, bad = 0;
        #pragma unroll
        for (int s = 0; s < SLICES; ++s) {
            int c = s_cnts[s];
            if (c > CAP_BLK) bad = 1;
            s_off[s] = acc;
            acc += min(c, CAP_BLK);
        }
        s_off[SLICES] = acc;
        if (acc < TOPK_) bad = 1;
        s_bad = bad;
    }
    __syncthreads();

    int cnt;
    if (!s_bad) {
        cnt = s_off[SLICES];
        // gather: wave w copies segments w, w+4, ... (<=32 floats each)
        const int wave = tid >> 6, lane = tid & 63;
        for (int s = wave; s < SLICES; s += 4) {
            int c = min(s_cnts[s], CAP_BLK);
            if (lane < c)
                s_cand[s_off[s] + lane] =
                    ws_cand[(size_t)(row * SLICES + s) * CAP_BLK + lane];
        }
        __syncthreads();
    } else {
        // exact histogram fallback (astronomically rare for uniform data)
        unsigned* s_hist = (unsigned*)s_cand;
        for (int i = tid; i < NHIST; i += 256) s_hist[i] = 0u;
        if (tid == 0) s_cnt = 0;
        __syncthreads();
        const float4* rp4 = (const float4*)rp;
        for (int i = tid; i < NF4; i += 256) {
            float4 v = rp4[i];
            float xs[4] = {v.x, v.y, v.z, v.w};
            #pragma unroll
            for (int c = 0; c < 4; ++c) {
                int b = (int)(xs[c] * (float)NHIST);
                b = min(max(b, 0), NHIST - 1);
                atomicAdd(&s_hist[b], 1u);
            }
        }
        __syncthreads();
        if (tid == 0) {
            for (int j = 0; j < T_; ++j) {
                int id = s_ids[j];
                bool dup = false;
                for (int q = 0; q < j; ++q) dup = dup || (s_ids[q] == id);
                if (!dup) {
                    int b = (int)(rp[id] * (float)NHIST);
                    b = min(max(b, 0), NHIST - 1);
                    s_hist[b]--;
                }
            }
            int acc = 0, b = NHIST - 1;
            for (; b >= 0; --b) {
                acc += (int)s_hist[b];
                if (acc >= TOPK_) break;
            }
            s_bstar = max(b, 0);
        }
        __syncthreads();
        int bstar = s_bstar;
        for (int i = tid; i < NF4; i += 256) {
            float4 v = rp4[i];
            int col = i << 2;
            float xs[4] = {v.x, v.y, v.z, v.w};
            #pragma unroll
            for (int c = 0; c < 4; ++c) {
                float x = xs[c];
                int b = (int)(x * (float)NHIST);
                b = min(max(b, 0), NHIST - 1);
                if (b >= bstar) {
                    int cc = col + c;
                    bool is_t = false;
                    #pragma unroll
                    for (int j = 0; j < T_; ++j) is_t |= (cc == s_ids[j]);
                    if (!is_t) {
                        int k = atomicAdd(&s_cnt, 1);
                        if (k < NHIST) s_cand[k] = x;
                    }
                }
            }
        }
        __syncthreads();
        cnt = min(s_cnt, NHIST);
    }

    // ---- O(n^2) exact rank-select (n ~ 240): include x_i iff rank < TOPK_.
    // Inner index j is wave-uniform -> LDS broadcast, conflict-free.
    float sum = 0.f;
    for (int i = tid; i < cnt; i += 256) {
        float x = s_cand[i];
        int rank = 0;
        for (int j = 0; j < cnt; ++j) {
            float y = s_cand[j];
            rank += (y > x) ? 1 : ((y == x && j < i) ? 1 : 0);
        }
        if (rank < TOPK_) sum += x;
    }

    #pragma unroll
    for (int off = 32; off > 0; off >>= 1) sum += __shfl_down(sum, off);
    if ((tid & 63) == 0) s_red[tid >> 6] = sum;
    __syncthreads();
    if (tid == 0) {
        float tot = s_red[0] + s_red[1] + s_red[2] + s_red[3];
        atomicAdd(out + 2, tot * (1.0f / (B_ * TOPK_)));
    }
}

extern "C" void kernel_launch(void* const* d_in, const int* in_sizes, int n_in,
                              void* d_out, int out_size, void* d_ws, size_t ws_size,
                              hipStream_t stream) {
    const float* sparse  = (const float*)d_in[0];
    const int*   tids    = (const int*)d_in[1];
    float*       out     = (float*)d_out;
    int*         ws_bcnt = (int*)d_ws;
    float*       ws_cand = (float*)((char*)d_ws + 32768);

    collect_kernel<<<NBLK, 256, 0, stream>>>(sparse, tids, ws_cand, ws_bcnt, out);
    reduce_kernel<<<B_, 256, 0, stream>>>(sparse, tids, ws_cand, ws_bcnt, out);
}